// Round 11
// baseline (237.144 us; speedup 1.0000x reference)
//
#include <hip/hip_runtime.h>

// SelfAttentiveLBLBiLM on MI355X — round 18.
// r17 post-mortem: hw variants all within noise (232.6-236.4); hw question
// closed. Cross-structure accounting (r13: 572-418-44 => prep~108; r11/r14:
// 236-44-90modeled => prep~100) converges on PREP as the largest improvable
// cost (~100us vs ~30us roofline). Cause: k_prep_w does 4B scalar loads +
// 2B scalar stores per element (never vectorized), 32x32 tiles; k_prep_x
// 8 elems/thread. This round (optimization-as-diagnostic):
//  - k_prep_w: 64x64 tiles, float4 loads, LDS [64][65] (pad 65 -> 2-way
//    bank aliasing = free), 8-float gather -> uint4 stores. 1024 blocks.
//  - k_prep_x: 16 elems/thread, 4x float4 in -> 2x uint4 out.
// Output bitwise identical. If total doesn't drop, residual is harness-side
// and we're at the floor.
// Dispatches: prep_w(v2), prep_x(v2), qkv(128^2+swz), attn(4-row),
// proj+rel(128^2 sliding), hw 128^2 2-phase x2 (gate via LDS).

#define B_ 8
#define S_ 1024
#define D_ 512
#define H_ 8
#define DK_ 64
#define WIDTH_ 8
#define S2_ 1040
#define NHW_ 2

typedef short bf16x8 __attribute__((ext_vector_type(8)));
typedef float f32x4 __attribute__((ext_vector_type(4)));

__device__ __forceinline__ float us2f(unsigned short u) {
  union { unsigned int i; float f; } c; c.i = ((unsigned int)u) << 16; return c.f;
}
__device__ __forceinline__ unsigned short f2us(float f) {
  union { float f; unsigned int i; } c; c.f = f;
  unsigned int x = c.i;
  return (unsigned short)((x + 0x7fffu + ((x >> 16) & 1u)) >> 16);
}
__device__ __forceinline__ unsigned int pack2(float a, float b) {
  return (unsigned int)f2us(a) | ((unsigned int)f2us(b) << 16);
}
__device__ __forceinline__ void async16(const void* g, void* l) {
  __builtin_amdgcn_global_load_lds(
      (const __attribute__((address_space(1))) void*)g,
      (__attribute__((address_space(3))) void*)l, 16, 0, 0);
}
__device__ __forceinline__ void unpack8(uint4 u, float* f) {
  unsigned int w[4] = {u.x, u.y, u.z, u.w};
  #pragma unroll
  for (int c = 0; c < 4; ++c) {
    union { unsigned int i; float g; } lo, hi;
    lo.i = w[c] << 16;
    hi.i = w[c] & 0xffff0000u;
    f[2 * c] = lo.g;
    f[2 * c + 1] = hi.g;
  }
}

// ---------------------------------------------------------------------------
// Prep (weights) v2: 64x64 fp32 tiles, vectorized.
// [0,512): attn transpose (8 slices x 8x8 tiles).
// [512,1024): hw transpose + r7 (nl,g) pairing (4 slices x 8x16 tiles).
__global__ __launch_bounds__(256) void k_prep_w(
    const float* __restrict__ lW, const float* __restrict__ rW,
    const float* __restrict__ lhwW, const float* __restrict__ rhwW,
    unsigned short* __restrict__ WTall, unsigned short* __restrict__ WTp,
    unsigned short* __restrict__ hWT)
{
  __shared__ float tile[64][65];       // pad 65 (==1 mod 32): 2-way = free
  const size_t DD = (size_t)D_ * D_;
  const int bx = blockIdx.x;
  const int tid = threadIdx.x;

  const float* src;
  int r0, c0, ldsrc, side = 0, slice = 0, sl = 0;
  if (bx < 512) {                      // attn: src (512,512) fp32
    sl = bx >> 6; int rem = bx & 63;
    side = sl >> 2; slice = sl & 3;
    r0 = (rem >> 3) * 64; c0 = (rem & 7) * 64;
    src = (side ? rW : lW) + (size_t)slice * DD;
    ldsrc = 512;
  } else {                             // hw: src (512,1024) fp32
    int idx = bx - 512;
    sl = idx >> 7; int rem = idx & 127;
    r0 = (rem >> 4) * 64; c0 = (rem & 15) * 64;
    src = ((sl >> 1) ? rhwW : lhwW) + (size_t)(sl & 1) * 512 * 1024;
    ldsrc = 1024;
  }

  // load 64x64 tile: float4 per lane, 4 passes of 16 rows
  {
    const int r = tid >> 4;            // 0..15
    const int c4 = (tid & 15) * 4;
    #pragma unroll
    for (int p = 0; p < 4; ++p) {
      float4 v = *reinterpret_cast<const float4*>(
          &src[(size_t)(r0 + p * 16 + r) * ldsrc + c0 + c4]);
      tile[p * 16 + r][c4 + 0] = v.x;
      tile[p * 16 + r][c4 + 1] = v.y;
      tile[p * 16 + r][c4 + 2] = v.z;
      tile[p * 16 + r][c4 + 3] = v.w;
    }
  }
  __syncthreads();

  // transposed store: out row = source col c0+oc; 8 uint4 per row (64 shorts)
  #pragma unroll
  for (int p = 0; p < 2; ++p) {
    int idx = p * 256 + tid;
    int oc = idx >> 3;                 // 0..63
    int seg = idx & 7;                 // covers source rows seg*8..seg*8+7
    int c = c0 + oc;
    float f[8];
    #pragma unroll
    for (int k = 0; k < 8; ++k) f[k] = tile[seg * 8 + k][oc];
    uint4 o;
    o.x = pack2(f[0], f[1]); o.y = pack2(f[2], f[3]);
    o.z = pack2(f[4], f[5]); o.w = pack2(f[6], f[7]);
    if (bx < 512) {
      unsigned short* dst = (slice < 3)
          ? WTall + (size_t)(side * 3 + slice) * DD
          : WTp + (size_t)side * DD;
      *reinterpret_cast<uint4*>(&dst[(size_t)c * 512 + r0 + seg * 8]) = o;
    } else {
      unsigned short* dst = hWT + (size_t)sl * 1024 * 512;
      int q = (2 * ((c & 511) >> 4) + (c >= 512 ? 1 : 0)) * 16 + (c & 15);
      *reinterpret_cast<uint4*>(&dst[(size_t)q * 512 + r0 + seg * 8]) = o;
    }
  }
}

// ---------------------------------------------------------------------------
// Prep (activations) v2: 16 elems/thread; build new_in + qkv bias tail.
__global__ __launch_bounds__(256) void k_prep_x(
    const float* __restrict__ x,
    const float* __restrict__ lpad, const float* __restrict__ rpad,
    const float* __restrict__ lb, const float* __restrict__ rb,
    unsigned short* __restrict__ nin, float* __restrict__ qkvbias)
{
  int gid = blockIdx.x * 256 + threadIdx.x;
  const int NTH = B_ * S2_ * 32;       // 266,240
  if (gid >= NTH) {
    int t = gid - NTH;
    if (t < 1536) qkvbias[t] = lb[t];
    else if (t < 3072) qkvbias[t] = rb[t - 1536];
    return;
  }
  int c16 = (gid & 31) << 4;
  int row = gid >> 5;
  int b = row / S2_;
  int t = row - b * S2_;
  const float* src;
  if (t < WIDTH_)            src = lpad + (size_t)t * D_ + c16;
  else if (t >= S_ + WIDTH_) src = rpad + (size_t)(t - S_ - WIDTH_) * D_ + c16;
  else                       src = x + ((size_t)b * S_ + (t - WIDTH_)) * D_ + c16;
  float4 a = *reinterpret_cast<const float4*>(src);
  float4 c = *reinterpret_cast<const float4*>(src + 4);
  float4 d = *reinterpret_cast<const float4*>(src + 8);
  float4 e = *reinterpret_cast<const float4*>(src + 12);
  uint4 o1, o2;
  o1.x = pack2(a.x, a.y); o1.y = pack2(a.z, a.w);
  o1.z = pack2(c.x, c.y); o1.w = pack2(c.z, c.w);
  o2.x = pack2(d.x, d.y); o2.y = pack2(d.z, d.w);
  o2.z = pack2(e.x, e.y); o2.w = pack2(e.z, e.w);
  unsigned short* dp = nin + (size_t)row * D_ + c16;
  *reinterpret_cast<uint4*>(dp) = o1;
  *reinterpret_cast<uint4*>(dp + 8) = o2;
}

// ---------------------------------------------------------------------------
// MFMA GEMM (QKV): C(M,N) = A(M,K) @ BT(N,K)^T + bias(N).
// BK=64, XOR-swizzled LDS, tile 128x128, 4 waves, XCD-swizzled grid.
__global__ __launch_bounds__(256) void k_gemm_mfma(
    const unsigned short* __restrict__ A,
    const unsigned short* __restrict__ BT,
    const float* __restrict__ bias,
    unsigned short* __restrict__ C,
    int M, int N, int K)
{
  __shared__ unsigned short As[128 * 64];
  __shared__ unsigned short Bs[128 * 64];

  const int tid = threadIdx.x;
  const int w = tid >> 6;
  const int l = tid & 63;

  // bijective XCD swizzle (nwg % 8 == 0)
  const int gx = gridDim.x;
  const int nwg = gx * gridDim.y;
  const int flat = blockIdx.y * gx + blockIdx.x;
  const int cpx = nwg >> 3;
  const int nf = (flat & 7) * cpx + (flat >> 3);
  const int bm = (nf / gx) * 128;
  const int bn = (nf % gx) * 128;

  const int wrow = (w >> 1) * 64;
  const int wcol = (w & 1) * 64;

  const int lr = l >> 3;
  const int sk = (((l & 7) ^ lr) & 7) * 8;
  const unsigned short* Ap = A + (size_t)(bm + w * 8 + lr) * K + sk;
  const unsigned short* Bp = BT + (size_t)(bn + w * 8 + lr) * K + sk;
  unsigned short* lA = &As[w * 512];
  unsigned short* lB = &Bs[w * 512];
  const size_t K32 = (size_t)32 * K;

  const int fl = l & 15;
  const int fq = l >> 4;
  const int fx = fl & 7;

  f32x4 acc[4][4];
  #pragma unroll
  for (int mi = 0; mi < 4; ++mi)
    #pragma unroll
    for (int ni = 0; ni < 4; ++ni) acc[mi][ni] = (f32x4){0.f, 0.f, 0.f, 0.f};

  for (int k0 = 0; k0 < K; k0 += 64) {
    #pragma unroll
    for (int r = 0; r < 4; ++r) {
      async16(Ap + k0 + r * K32, lA + r * 2048);
      async16(Bp + k0 + r * K32, lB + r * 2048);
    }
    __syncthreads();
    #pragma unroll
    for (int s = 0; s < 2; ++s) {
      bf16x8 af[4], bfr[4];
      #pragma unroll
      for (int mi = 0; mi < 4; ++mi)
        af[mi] = *reinterpret_cast<const bf16x8*>(
            &As[(wrow + mi * 16 + fl) * 64 + (((s * 4 + fq) ^ fx) * 8)]);
      #pragma unroll
      for (int ni = 0; ni < 4; ++ni)
        bfr[ni] = *reinterpret_cast<const bf16x8*>(
            &Bs[(wcol + ni * 16 + fl) * 64 + (((s * 4 + fq) ^ fx) * 8)]);
      #pragma unroll
      for (int mi = 0; mi < 4; ++mi)
        #pragma unroll
        for (int ni = 0; ni < 4; ++ni)
          acc[mi][ni] = __builtin_amdgcn_mfma_f32_16x16x32_bf16(
              af[mi], bfr[ni], acc[mi][ni], 0, 0, 0);
    }
    __syncthreads();
  }

  float bv[4];
  #pragma unroll
  for (int ni = 0; ni < 4; ++ni) bv[ni] = bias[bn + wcol + ni * 16 + fl];

  const int rbase = (l >> 4) * 4;
  #pragma unroll
  for (int mi = 0; mi < 4; ++mi) {
    #pragma unroll
    for (int r = 0; r < 4; ++r) {
      int row = bm + wrow + mi * 16 + rbase + r;
      unsigned short* Cp = C + (size_t)row * N + bn + wcol + fl;
      #pragma unroll
      for (int ni = 0; ni < 4; ++ni)
        Cp[ni * 16] = f2us(acc[mi][ni][r] + bv[ni]);
    }
  }
}

// ---------------------------------------------------------------------------
// Highway GEMM 128^2 2-phase + fused gate, gate-xv via 16KB LDS slice.
// BT rows pair (nl,g) via r7 mapping; out col oc = (bn+wcol)/2 + p*16 + fl.
template <bool FINAL>
__global__ __launch_bounds__(256) void k_gemm_hw(
    const unsigned short* __restrict__ Xsrc,
    const unsigned short* __restrict__ BTb, size_t bStrZ,
    const float* __restrict__ bias0, const float* __restrict__ bias1,
    unsigned short* __restrict__ Obf,
    float* __restrict__ Ofp)
{
  __shared__ unsigned short As[128 * 64];
  __shared__ unsigned short Bs[128 * 64];
  const int K = 512;
  const size_t MS = (size_t)B_ * S_ * D_;

  const int z = blockIdx.z;
  const unsigned short* A = Xsrc + (size_t)z * MS;
  const unsigned short* BT = BTb + (size_t)z * bStrZ;
  const float* bias = z ? bias1 : bias0;

  const int tid = threadIdx.x;
  const int w = tid >> 6;
  const int l = tid & 63;

  // XCD swizzle within z-plane (512 blocks, %8==0)
  const int gx = gridDim.x;
  const int nwg = gx * gridDim.y;
  const int flat = blockIdx.y * gx + blockIdx.x;
  const int cpx = nwg >> 3;
  const int nf = (flat & 7) * cpx + (flat >> 3);
  const int bm = (nf / gx) * 128;
  const int bn = (nf % gx) * 128;

  const int wrow = (w >> 1) * 64;
  const int wcol = (w & 1) * 64;

  const int lr = l >> 3;
  const int sk = (((l & 7) ^ lr) & 7) * 8;
  const unsigned short* Ap = A + (size_t)(bm + w * 8 + lr) * K + sk;
  const unsigned short* Bp = BT + (size_t)(bn + w * 8 + lr) * K + sk;
  unsigned short* lA = &As[w * 512];
  unsigned short* lB = &Bs[w * 512];
  const size_t K32 = (size_t)32 * K;

  const int fl = l & 15;
  const int fq = l >> 4;
  const int fx = fl & 7;

  f32x4 acc[4][4];
  #pragma unroll
  for (int mi = 0; mi < 4; ++mi)
    #pragma unroll
    for (int ni = 0; ni < 4; ++ni) acc[mi][ni] = (f32x4){0.f, 0.f, 0.f, 0.f};

  for (int k0 = 0; k0 < K; k0 += 64) {
    #pragma unroll
    for (int r = 0; r < 4; ++r) {
      async16(Ap + k0 + r * K32, lA + r * 2048);
      async16(Bp + k0 + r * K32, lB + r * 2048);
    }
    __syncthreads();
    #pragma unroll
    for (int s = 0; s < 2; ++s) {
      bf16x8 af[4], bfr[4];
      #pragma unroll
      for (int mi = 0; mi < 4; ++mi)
        af[mi] = *reinterpret_cast<const bf16x8*>(
            &As[(wrow + mi * 16 + fl) * 64 + (((s * 4 + fq) ^ fx) * 8)]);
      #pragma unroll
      for (int ni = 0; ni < 4; ++ni)
        bfr[ni] = *reinterpret_cast<const bf16x8*>(
            &Bs[(wcol + ni * 16 + fl) * 64 + (((s * 4 + fq) ^ fx) * 8)]);
      #pragma unroll
      for (int mi = 0; mi < 4; ++mi)
        #pragma unroll
        for (int ni = 0; ni < 4; ++ni)
          acc[mi][ni] = __builtin_amdgcn_mfma_f32_16x16x32_bf16(
              af[mi], bfr[ni], acc[mi][ni], 0, 0, 0);
    }
    __syncthreads();
  }

  // ---- gate-slice stage: A[bm..bm+128) x [bn/2 .. bn/2+64) -> As (16KB).
  // LDS short s of row holds global col short (bn/2) + (s ^ ((row&12)<<2)).
  {
    const unsigned short* gs = A + (size_t)bm * 512 + (bn >> 1);
    #pragma unroll
    for (int i = 0; i < 4; ++i) {
      int row = i * 32 + (tid >> 3);
      int cb = tid & 7;
      int ss = (cb * 8) ^ ((row & 12) << 2);
      async16(gs + (size_t)row * 512 + ss, &As[row * 64 + cb * 8]);
    }
  }
  asm volatile("s_waitcnt vmcnt(0)" ::: "memory");
  __syncthreads();

  // ---- gate epilogue (xv from LDS, 2-way max bank aliasing = free)
  const int ocb = ((bn + wcol) >> 1) + fl;
  float bnl[2], bg[2];
  #pragma unroll
  for (int p = 0; p < 2; ++p) {
    bnl[p] = bias[ocb + p * 16];
    bg[p]  = bias[512 + ocb + p * 16];
  }
  const int rbase = fq * 4;
  const int crel0 = (wcol >> 1) + fl;
  #pragma unroll
  for (int mi = 0; mi < 4; ++mi) {
    #pragma unroll
    for (int r = 0; r < 4; ++r) {
      int lrow = wrow + mi * 16 + rbase + r;
      int row = bm + lrow;
      #pragma unroll
      for (int p = 0; p < 2; ++p) {
        int oc = ocb + p * 16;
        float xv = us2f(As[lrow * 64 + ((crel0 + p * 16) ^ ((lrow & 12) << 2))]);
        float nl = fmaxf(acc[mi][2 * p][r] + bnl[p], 0.f);
        float g  = 1.f / (1.f + __expf(-(acc[mi][2 * p + 1][r] + bg[p])));
        float res = g * xv + (1.f - g) * nl;
        if (FINAL) Ofp[(size_t)row * 1024 + z * 512 + oc] = res;
        else       Obf[(size_t)z * MS + (size_t)row * 512 + oc] = f2us(res);
      }
    }
  }
}

// ---------------------------------------------------------------------------
// Proj GEMM + fused rel-add (128^2 structure, sliding-window rel-add).
__global__ __launch_bounds__(256) void k_gemm_proj(
    const unsigned short* __restrict__ ctx,
    const unsigned short* __restrict__ WTp,    // (2,512,512)
    const unsigned short* __restrict__ nin,    // (B,S2,512)
    const float* __restrict__ lb3, const float* __restrict__ rb3,
    const float* __restrict__ wrel0, const float* __restrict__ wrel1,
    unsigned short* __restrict__ hwx)          // (2,8192,512)
{
  __shared__ unsigned short smem[128 * 136];   // 34.8 KB; staging uses 32 KB
  unsigned short* As = smem;
  unsigned short* Bs = smem + 8192;
  const int K = 512;
  const size_t MS = (size_t)B_ * S_ * D_;

  const int z = blockIdx.z;
  const unsigned short* A = ctx + (size_t)z * MS;
  const unsigned short* BT = WTp + (size_t)z * 512 * 512;
  const float* bias = z ? rb3 : lb3;
  const float* wrel = z ? wrel1 : wrel0;
  const int off = z * WIDTH_;

  const int tid = threadIdx.x;
  const int w = tid >> 6;
  const int l = tid & 63;
  const int bm = blockIdx.y * 128;
  const int bn = blockIdx.x * 128;
  const int wrow = (w >> 1) * 64;
  const int wcol = (w & 1) * 64;

  const int lr = l >> 3;
  const int sk = (((l & 7) ^ lr) & 7) * 8;
  const unsigned short* Ap = A + (size_t)(bm + w * 8 + lr) * K + sk;
  const unsigned short* Bp = BT + (size_t)(bn + w * 8 + lr) * K + sk;
  unsigned short* lA = &As[w * 512];
  unsigned short* lB = &Bs[w * 512];
  const size_t K32 = (size_t)32 * K;

  const int fl = l & 15;
  const int fq = l >> 4;
  const int fx = fl & 7;

  f32x4 acc[4][4];
  #pragma unroll
  for (int mi = 0; mi < 4; ++mi)
    #pragma unroll
    for (int ni = 0; ni < 4; ++ni) acc[mi][ni] = (f32x4){0.f, 0.f, 0.f, 0.f};

  for (int k0 = 0; k0 < K; k0 += 64) {
    #pragma unroll
    for (int r = 0; r < 4; ++r) {
      async16(Ap + k0 + r * K32, lA + r * 2048);
      async16(Bp + k0 + r * K32, lB + r * 2048);
    }
    __syncthreads();
    #pragma unroll
    for (int s = 0; s < 2; ++s) {
      bf16x8 af[4], bfr[4];
      #pragma unroll
      for (int mi = 0; mi < 4; ++mi)
        af[mi] = *reinterpret_cast<const bf16x8*>(
            &As[(wrow + mi * 16 + fl) * 64 + (((s * 4 + fq) ^ fx) * 8)]);
      #pragma unroll
      for (int ni = 0; ni < 4; ++ni)
        bfr[ni] = *reinterpret_cast<const bf16x8*>(
            &Bs[(wcol + ni * 16 + fl) * 64 + (((s * 4 + fq) ^ fx) * 8)]);
      #pragma unroll
      for (int mi = 0; mi < 4; ++mi)
        #pragma unroll
        for (int ni = 0; ni < 4; ++ni)
          acc[mi][ni] = __builtin_amdgcn_mfma_f32_16x16x32_bf16(
              af[mi], bfr[ni], acc[mi][ni], 0, 0, 0);
    }
    __syncthreads();
  }

  // stage bias-added tile into LDS (bf16, ld 136)
  float bv[4];
  #pragma unroll
  for (int ni = 0; ni < 4; ++ni) bv[ni] = bias[bn + wcol + ni * 16 + fl];
  const int rbase = (l >> 4) * 4;
  #pragma unroll
  for (int mi = 0; mi < 4; ++mi)
    #pragma unroll
    for (int r = 0; r < 4; ++r)
      #pragma unroll
      for (int ni = 0; ni < 4; ++ni)
        smem[(wrow + mi * 16 + rbase + r) * 136 + wcol + ni * 16 + fl] =
            f2us(acc[mi][ni][r] + bv[ni]);
  __syncthreads();

  // sliding-window rel-add: thread = (8-consecutive-row group, 8-col chunk).
  const float wj[9] = {wrel[0], wrel[1], wrel[2], wrel[3], wrel[4],
                       wrel[5], wrel[6], wrel[7], wrel[8]};
  const int g8 = (tid >> 4) * 8;
  const int tcol = (tid & 15) * 8;
  {
    int gr0 = bm + g8;
    int b0 = gr0 >> 10, s0 = gr0 & (S_ - 1);
    const unsigned short* np =
        nin + ((size_t)b0 * S2_ + off + s0) * D_ + bn + tcol;
    unsigned short* op = hwx + (size_t)z * MS + (size_t)gr0 * D_ + bn + tcol;
    #pragma unroll
    for (int h = 0; h < 2; ++h) {          // rows h*4 .. h*4+3 of the group
      float a4[4][8];
      #pragma unroll
      for (int i = 0; i < 4; ++i)
        unpack8(*reinterpret_cast<const uint4*>(
            &smem[(g8 + h * 4 + i) * 136 + tcol]), a4[i]);
      #pragma unroll
      for (int t = 0; t < 12; ++t) {       // absolute taps h*4 .. h*4+11
        float nf[8];
        unpack8(*reinterpret_cast<const uint4*>(
            np + (size_t)(h * 4 + t) * D_), nf);
        #pragma unroll
        for (int i = 0; i < 4; ++i) {
          if (t < i || t > i + 8) continue;
          float wv = wj[t - i];
          #pragma unroll
          for (int e = 0; e < 8; ++e) a4[i][e] += wv * nf[e];
        }
      }
      #pragma unroll
      for (int i = 0; i < 4; ++i) {
        uint4 o;
        o.x = pack2(a4[i][0], a4[i][1]); o.y = pack2(a4[i][2], a4[i][3]);
        o.z = pack2(a4[i][4], a4[i][5]); o.w = pack2(a4[i][6], a4[i][7]);
        *reinterpret_cast<uint4*>(op + (size_t)(h * 4 + i) * D_) = o;
      }
    }
  }
}

// ---------------------------------------------------------------------------
// Windowed attention, 4 consecutive rows per wave sharing a 13-row K/V
// window (r11-proven).
__global__ __launch_bounds__(256) void k_attn_window(
    const unsigned short* __restrict__ qkv,
    unsigned short* __restrict__ ctx)
{
  int wid = (blockIdx.x * 256 + threadIdx.x) >> 6;   // dir*2048 + b*256 + sg
  int lane = threadIdx.x & 63;
  int sg = wid & 255;
  int b = (wid >> 8) & 7;
  int dir = wid >> 11;
  int s0 = sg << 2;
  int i0 = s0 + WIDTH_;

  const size_t base = (size_t)b * S2_ * 3072 + dir * 1536;
  const int c0 = lane * 8;

  float qf[4][8];
  #pragma unroll
  for (int r = 0; r < 4; ++r)
    unpack8(*reinterpret_cast<const uint4*>(
        qkv + base + (size_t)(i0 + r) * 3072 + c0), qf[r]);

  float sc[4][10];
  float mx[4] = {-1e30f, -1e30f, -1e30f, -1e30f};
  #pragma unroll
  for (int t = 0; t < 13; ++t) {
    int j = (dir == 0) ? (i0 - 9 + t) : (i0 + t);
    bool ok = (j >= 0 && j < S2_);           // wave-uniform
    float kf[8];
    if (ok)
      unpack8(*reinterpret_cast<const uint4*>(
          qkv + base + (size_t)j * 3072 + 512 + c0), kf);
    #pragma unroll
    for (int r = 0; r < 4; ++r) {
      if (t < r || t > r + 9) continue;      // compile-time prune
      float sv = -1e30f;
      if (ok) {
        float p = qf[r][0] * kf[0];
        #pragma unroll
        for (int e = 1; e < 8; ++e) p += qf[r][e] * kf[e];
        p += __shfl_xor(p, 1);
        p += __shfl_xor(p, 2);
        p += __shfl_xor(p, 4);
        sv = p * 0.125f;
      }
      sc[r][t - r] = sv;
      mx[r] = fmaxf(mx[r], sv);
    }
  }

  float inv[4];
  #pragma unroll
  for (int r = 0; r < 4; ++r) {
    float den = 0.f;
    #pragma unroll
    for (int u = 0; u < 10; ++u) {
      sc[r][u] = (sc[r][u] > -1e29f) ? __expf(sc[r][u] - mx[r]) : 0.f;
      den += sc[r][u];
    }
    inv[r] = 1.f / den;
  }

  float acc[4][8];
  #pragma unroll
  for (int r = 0; r < 4; ++r)
    #pragma unroll
    for (int e = 0; e < 8; ++e) acc[r][e] = 0.f;

  #pragma unroll
  for (int t = 0; t < 13; ++t) {
    int j = (dir == 0) ? (i0 - 9 + t) : (i0 + t);
    bool ok = (j >= 0 && j < S2_);
    float vf[8];
    if (ok)
      unpack8(*reinterpret_cast<const uint4*>(
          qkv + base + (size_t)j * 3072 + 1024 + c0), vf);
    #pragma unroll
    for (int r = 0; r < 4; ++r) {
      if (t < r || t > r + 9) continue;
      if (ok) {
        float p = sc[r][t - r];
        #pragma unroll
        for (int e = 0; e < 8; ++e) acc[r][e] += p * vf[e];
      }
    }
  }

  #pragma unroll
  for (int r = 0; r < 4; ++r) {
    uint4 o;
    o.x = pack2(acc[r][0] * inv[r], acc[r][1] * inv[r]);
    o.y = pack2(acc[r][2] * inv[r], acc[r][3] * inv[r]);
    o.z = pack2(acc[r][4] * inv[r], acc[r][5] * inv[r]);
    o.w = pack2(acc[r][6] * inv[r], acc[r][7] * inv[r]);
    *reinterpret_cast<uint4*>(
        ctx + (((size_t)dir * B_ + b) * S_ + s0 + r) * D_ + c0) = o;
  }
}

// ---------------------------------------------------------------------------
extern "C" void kernel_launch(void* const* d_in, const int* in_sizes, int n_in,
                              void* d_out, int out_size, void* d_ws, size_t ws_size,
                              hipStream_t stream) {
  const float* x    = (const float*)d_in[0];
  const float* lW   = (const float*)d_in[1];
  const float* lb   = (const float*)d_in[2];
  const float* rW   = (const float*)d_in[3];
  const float* rb   = (const float*)d_in[4];
  const float* lpad = (const float*)d_in[5];
  const float* rpad = (const float*)d_in[6];
  const float* lw   = (const float*)d_in[7];
  const float* rw   = (const float*)d_in[8];
  const float* lhwW = (const float*)d_in[9];
  const float* lhwb = (const float*)d_in[10];
  const float* rhwW = (const float*)d_in[11];
  const float* rhwb = (const float*)d_in[12];
  float* out = (float*)d_out;
  unsigned short* ws = (unsigned short*)d_ws;

  const size_t NIN  = (size_t)B_ * S2_ * D_;       // 4,259,840
  const size_t NQKV = (size_t)B_ * S2_ * 3072;     // 25,559,040
  const size_t MS   = (size_t)B_ * S_ * D_;        // 4,194,304
  const size_t DD   = (size_t)D_ * D_;             // 262,144
  const size_t LHW  = (size_t)1024 * 512;          // 524,288

  unsigned short* nin   = ws;
  unsigned short* qkv   = nin + NIN;
  unsigned short* ctx   = qkv + NQKV;              // (2,B,S,D)
  unsigned short* hwx   = ctx + 2 * MS;            // (2,B,S,D)
  unsigned short* hwy   = hwx + 2 * MS;            // (2,B,S,D)
  unsigned short* WTall = hwy + 2 * MS;            // (3072,512)
  unsigned short* WTp   = WTall + 6 * DD;          // (2,512,512)
  unsigned short* hWT   = WTp + 2 * DD;            // (2,2,1024,512)
  float* qkvbias        = (float*)(hWT + 4 * LHW); // 3072 fp32

  // --- prep: 2 dispatches (vectorized v2) ---
  k_prep_w<<<1024, 256, 0, stream>>>(lW, rW, lhwW, rhwW, WTall, WTp, hWT);
  k_prep_x<<<1052, 256, 0, stream>>>(x, lpad, rpad, lb, rb, nin, qkvbias);

  const int MQ = B_ * S2_;   // 8320

  // --- fused QKV both sides: (8320 x 3072), 128^2 2-phase + XCD swizzle ---
  {
    dim3 g(3072 / 128, MQ / 128, 1);   // (24, 65) -> 1560 blocks, %8==0
    k_gemm_mfma<<<g, 256, 0, stream>>>(nin, WTall, qkvbias, qkv, MQ, 3072, D_);
  }

  // --- attention, both sides, 4 rows/wave ---
  k_attn_window<<<(2 * B_ * S_) / 16, 256, 0, stream>>>(qkv, ctx);

  // --- proj + fused rel-add, z-batched over side (128^2 kernel) ---
  {
    dim3 g(D_ / 128, (B_ * S_) / 128, 2);   // (4, 64, 2)
    k_gemm_proj<<<g, 256, 0, stream>>>(ctx, WTp, nin, lb + 3 * D_, rb + 3 * D_,
                                       lw, rw, hwx);
  }

  // --- highway layers: 128^2 2-phase + fused gate (LDS xv), z-batched ---
  {
    dim3 g(1024 / 128, (B_ * S_) / 128, 2);   // (8, 64, 2) = 1024 blocks
    k_gemm_hw<false><<<g, 256, 0, stream>>>(hwx, hWT, 2 * LHW,
                                            lhwb, rhwb, hwy, nullptr);
    k_gemm_hw<true><<<g, 256, 0, stream>>>(hwy, hWT + LHW, 2 * LHW,
                                           lhwb + 1024, rhwb + 1024,
                                           nullptr, out);
  }
}

// Round 13
// 227.912 us; speedup vs baseline: 1.0405x; 1.0405x over previous
//
#include <hip/hip_runtime.h>

// SelfAttentiveLBLBiLM on MI355X — round 20.
// r19 post-mortem: FAILED (absmax 4.6) — attn XCD chunk used the 2048-block
// bijection on a 1024-block grid (nb=(bid&7)*256+bid>>3): half the row
// groups never computed, nb>=1024 gave dir in [0,3] -> OOB writes past ctx.
// ERRATA#11 lesson violated by a hard-coded constant. Fix: derive factor
// from gridDim: nb=(bid&7)*(gridDim.x>>3)+(bid>>3). Everything else from
// r19 kept (proj XCD swizzle verified bijective; merged prep = r18 bodies).
// Dispatches: prep, qkv(128^2+swz), attn(4-row+chunk FIXED),
// proj+rel(128^2 sliding+swz), hw 128^2 2-phase x2 (gate via LDS).

#define B_ 8
#define S_ 1024
#define D_ 512
#define H_ 8
#define DK_ 64
#define WIDTH_ 8
#define S2_ 1040
#define NHW_ 2

typedef short bf16x8 __attribute__((ext_vector_type(8)));
typedef float f32x4 __attribute__((ext_vector_type(4)));

__device__ __forceinline__ float us2f(unsigned short u) {
  union { unsigned int i; float f; } c; c.i = ((unsigned int)u) << 16; return c.f;
}
__device__ __forceinline__ unsigned short f2us(float f) {
  union { float f; unsigned int i; } c; c.f = f;
  unsigned int x = c.i;
  return (unsigned short)((x + 0x7fffu + ((x >> 16) & 1u)) >> 16);
}
__device__ __forceinline__ unsigned int pack2(float a, float b) {
  return (unsigned int)f2us(a) | ((unsigned int)f2us(b) << 16);
}
__device__ __forceinline__ void async16(const void* g, void* l) {
  __builtin_amdgcn_global_load_lds(
      (const __attribute__((address_space(1))) void*)g,
      (__attribute__((address_space(3))) void*)l, 16, 0, 0);
}
__device__ __forceinline__ void unpack8(uint4 u, float* f) {
  unsigned int w[4] = {u.x, u.y, u.z, u.w};
  #pragma unroll
  for (int c = 0; c < 4; ++c) {
    union { unsigned int i; float g; } lo, hi;
    lo.i = w[c] << 16;
    hi.i = w[c] & 0xffff0000u;
    f[2 * c] = lo.g;
    f[2 * c + 1] = hi.g;
  }
}

// ---------------------------------------------------------------------------
// Prep (merged): [0,512) attn W transpose; [512,1024) hw W transpose;
// [1024,2076) new_in build + qkv bias tail. All vectorized.
__global__ __launch_bounds__(256) void k_prep(
    const float* __restrict__ lW, const float* __restrict__ rW,
    const float* __restrict__ lhwW, const float* __restrict__ rhwW,
    const float* __restrict__ x,
    const float* __restrict__ lpad, const float* __restrict__ rpad,
    const float* __restrict__ lb, const float* __restrict__ rb,
    unsigned short* __restrict__ WTall, unsigned short* __restrict__ WTp,
    unsigned short* __restrict__ hWT,
    unsigned short* __restrict__ nin, float* __restrict__ qkvbias)
{
  __shared__ float tile[64][65];       // pad 65 (==1 mod 32): 2-way = free
  const size_t DD = (size_t)D_ * D_;
  const int bx = blockIdx.x;
  const int tid = threadIdx.x;

  if (bx >= 1024) {                    // ---- new_in + bias tail
    int gid = (bx - 1024) * 256 + tid;
    const int NTH = B_ * S2_ * 32;     // 266,240
    if (gid >= NTH) {
      int t = gid - NTH;
      if (t < 1536) qkvbias[t] = lb[t];
      else if (t < 3072) qkvbias[t] = rb[t - 1536];
      return;
    }
    int c16 = (gid & 31) << 4;
    int row = gid >> 5;
    int b = row / S2_;
    int t = row - b * S2_;
    const float* src;
    if (t < WIDTH_)            src = lpad + (size_t)t * D_ + c16;
    else if (t >= S_ + WIDTH_) src = rpad + (size_t)(t - S_ - WIDTH_) * D_ + c16;
    else                       src = x + ((size_t)b * S_ + (t - WIDTH_)) * D_ + c16;
    float4 a = *reinterpret_cast<const float4*>(src);
    float4 c = *reinterpret_cast<const float4*>(src + 4);
    float4 d = *reinterpret_cast<const float4*>(src + 8);
    float4 e = *reinterpret_cast<const float4*>(src + 12);
    uint4 o1, o2;
    o1.x = pack2(a.x, a.y); o1.y = pack2(a.z, a.w);
    o1.z = pack2(c.x, c.y); o1.w = pack2(c.z, c.w);
    o2.x = pack2(d.x, d.y); o2.y = pack2(d.z, d.w);
    o2.z = pack2(e.x, e.y); o2.w = pack2(e.z, e.w);
    unsigned short* dp = nin + (size_t)row * D_ + c16;
    *reinterpret_cast<uint4*>(dp) = o1;
    *reinterpret_cast<uint4*>(dp + 8) = o2;
    return;
  }

  // ---- weight transposes (64x64 fp32 tiles, vectorized)
  const float* src;
  int r0, c0, ldsrc, side = 0, slice = 0, sl = 0;
  if (bx < 512) {                      // attn: src (512,512) fp32
    sl = bx >> 6; int rem = bx & 63;
    side = sl >> 2; slice = sl & 3;
    r0 = (rem >> 3) * 64; c0 = (rem & 7) * 64;
    src = (side ? rW : lW) + (size_t)slice * DD;
    ldsrc = 512;
  } else {                             // hw: src (512,1024) fp32
    int idx = bx - 512;
    sl = idx >> 7; int rem = idx & 127;
    r0 = (rem >> 4) * 64; c0 = (rem & 15) * 64;
    src = ((sl >> 1) ? rhwW : lhwW) + (size_t)(sl & 1) * 512 * 1024;
    ldsrc = 1024;
  }

  {
    const int r = tid >> 4;            // 0..15
    const int c4 = (tid & 15) * 4;
    #pragma unroll
    for (int p = 0; p < 4; ++p) {
      float4 v = *reinterpret_cast<const float4*>(
          &src[(size_t)(r0 + p * 16 + r) * ldsrc + c0 + c4]);
      tile[p * 16 + r][c4 + 0] = v.x;
      tile[p * 16 + r][c4 + 1] = v.y;
      tile[p * 16 + r][c4 + 2] = v.z;
      tile[p * 16 + r][c4 + 3] = v.w;
    }
  }
  __syncthreads();

  #pragma unroll
  for (int p = 0; p < 2; ++p) {
    int idx = p * 256 + tid;
    int oc = idx >> 3;                 // 0..63
    int seg = idx & 7;                 // source rows seg*8..seg*8+7
    int c = c0 + oc;
    float f[8];
    #pragma unroll
    for (int k = 0; k < 8; ++k) f[k] = tile[seg * 8 + k][oc];
    uint4 o;
    o.x = pack2(f[0], f[1]); o.y = pack2(f[2], f[3]);
    o.z = pack2(f[4], f[5]); o.w = pack2(f[6], f[7]);
    if (bx < 512) {
      unsigned short* dst = (slice < 3)
          ? WTall + (size_t)(side * 3 + slice) * DD
          : WTp + (size_t)side * DD;
      *reinterpret_cast<uint4*>(&dst[(size_t)c * 512 + r0 + seg * 8]) = o;
    } else {
      unsigned short* dst = hWT + (size_t)sl * 1024 * 512;
      int q = (2 * ((c & 511) >> 4) + (c >= 512 ? 1 : 0)) * 16 + (c & 15);
      *reinterpret_cast<uint4*>(&dst[(size_t)q * 512 + r0 + seg * 8]) = o;
    }
  }
}

// ---------------------------------------------------------------------------
// MFMA GEMM (QKV): C(M,N) = A(M,K) @ BT(N,K)^T + bias(N).
// BK=64, XOR-swizzled LDS, tile 128x128, 4 waves, XCD-swizzled grid.
__global__ __launch_bounds__(256) void k_gemm_mfma(
    const unsigned short* __restrict__ A,
    const unsigned short* __restrict__ BT,
    const float* __restrict__ bias,
    unsigned short* __restrict__ C,
    int M, int N, int K)
{
  __shared__ unsigned short As[128 * 64];
  __shared__ unsigned short Bs[128 * 64];

  const int tid = threadIdx.x;
  const int w = tid >> 6;
  const int l = tid & 63;

  // bijective XCD swizzle (nwg % 8 == 0)
  const int gx = gridDim.x;
  const int nwg = gx * gridDim.y;
  const int flat = blockIdx.y * gx + blockIdx.x;
  const int cpx = nwg >> 3;
  const int nf = (flat & 7) * cpx + (flat >> 3);
  const int bm = (nf / gx) * 128;
  const int bn = (nf % gx) * 128;

  const int wrow = (w >> 1) * 64;
  const int wcol = (w & 1) * 64;

  const int lr = l >> 3;
  const int sk = (((l & 7) ^ lr) & 7) * 8;
  const unsigned short* Ap = A + (size_t)(bm + w * 8 + lr) * K + sk;
  const unsigned short* Bp = BT + (size_t)(bn + w * 8 + lr) * K + sk;
  unsigned short* lA = &As[w * 512];
  unsigned short* lB = &Bs[w * 512];
  const size_t K32 = (size_t)32 * K;

  const int fl = l & 15;
  const int fq = l >> 4;
  const int fx = fl & 7;

  f32x4 acc[4][4];
  #pragma unroll
  for (int mi = 0; mi < 4; ++mi)
    #pragma unroll
    for (int ni = 0; ni < 4; ++ni) acc[mi][ni] = (f32x4){0.f, 0.f, 0.f, 0.f};

  for (int k0 = 0; k0 < K; k0 += 64) {
    #pragma unroll
    for (int r = 0; r < 4; ++r) {
      async16(Ap + k0 + r * K32, lA + r * 2048);
      async16(Bp + k0 + r * K32, lB + r * 2048);
    }
    __syncthreads();
    #pragma unroll
    for (int s = 0; s < 2; ++s) {
      bf16x8 af[4], bfr[4];
      #pragma unroll
      for (int mi = 0; mi < 4; ++mi)
        af[mi] = *reinterpret_cast<const bf16x8*>(
            &As[(wrow + mi * 16 + fl) * 64 + (((s * 4 + fq) ^ fx) * 8)]);
      #pragma unroll
      for (int ni = 0; ni < 4; ++ni)
        bfr[ni] = *reinterpret_cast<const bf16x8*>(
            &Bs[(wcol + ni * 16 + fl) * 64 + (((s * 4 + fq) ^ fx) * 8)]);
      #pragma unroll
      for (int mi = 0; mi < 4; ++mi)
        #pragma unroll
        for (int ni = 0; ni < 4; ++ni)
          acc[mi][ni] = __builtin_amdgcn_mfma_f32_16x16x32_bf16(
              af[mi], bfr[ni], acc[mi][ni], 0, 0, 0);
    }
    __syncthreads();
  }

  float bv[4];
  #pragma unroll
  for (int ni = 0; ni < 4; ++ni) bv[ni] = bias[bn + wcol + ni * 16 + fl];

  const int rbase = (l >> 4) * 4;
  #pragma unroll
  for (int mi = 0; mi < 4; ++mi) {
    #pragma unroll
    for (int r = 0; r < 4; ++r) {
      int row = bm + wrow + mi * 16 + rbase + r;
      unsigned short* Cp = C + (size_t)row * N + bn + wcol + fl;
      #pragma unroll
      for (int ni = 0; ni < 4; ++ni)
        Cp[ni * 16] = f2us(acc[mi][ni][r] + bv[ni]);
    }
  }
}

// ---------------------------------------------------------------------------
// Highway GEMM 128^2 2-phase + fused gate, gate-xv via 16KB LDS slice.
template <bool FINAL>
__global__ __launch_bounds__(256) void k_gemm_hw(
    const unsigned short* __restrict__ Xsrc,
    const unsigned short* __restrict__ BTb, size_t bStrZ,
    const float* __restrict__ bias0, const float* __restrict__ bias1,
    unsigned short* __restrict__ Obf,
    float* __restrict__ Ofp)
{
  __shared__ unsigned short As[128 * 64];
  __shared__ unsigned short Bs[128 * 64];
  const int K = 512;
  const size_t MS = (size_t)B_ * S_ * D_;

  const int z = blockIdx.z;
  const unsigned short* A = Xsrc + (size_t)z * MS;
  const unsigned short* BT = BTb + (size_t)z * bStrZ;
  const float* bias = z ? bias1 : bias0;

  const int tid = threadIdx.x;
  const int w = tid >> 6;
  const int l = tid & 63;

  // XCD swizzle within z-plane (512 blocks, %8==0)
  const int gx = gridDim.x;
  const int nwg = gx * gridDim.y;
  const int flat = blockIdx.y * gx + blockIdx.x;
  const int cpx = nwg >> 3;
  const int nf = (flat & 7) * cpx + (flat >> 3);
  const int bm = (nf / gx) * 128;
  const int bn = (nf % gx) * 128;

  const int wrow = (w >> 1) * 64;
  const int wcol = (w & 1) * 64;

  const int lr = l >> 3;
  const int sk = (((l & 7) ^ lr) & 7) * 8;
  const unsigned short* Ap = A + (size_t)(bm + w * 8 + lr) * K + sk;
  const unsigned short* Bp = BT + (size_t)(bn + w * 8 + lr) * K + sk;
  unsigned short* lA = &As[w * 512];
  unsigned short* lB = &Bs[w * 512];
  const size_t K32 = (size_t)32 * K;

  const int fl = l & 15;
  const int fq = l >> 4;
  const int fx = fl & 7;

  f32x4 acc[4][4];
  #pragma unroll
  for (int mi = 0; mi < 4; ++mi)
    #pragma unroll
    for (int ni = 0; ni < 4; ++ni) acc[mi][ni] = (f32x4){0.f, 0.f, 0.f, 0.f};

  for (int k0 = 0; k0 < K; k0 += 64) {
    #pragma unroll
    for (int r = 0; r < 4; ++r) {
      async16(Ap + k0 + r * K32, lA + r * 2048);
      async16(Bp + k0 + r * K32, lB + r * 2048);
    }
    __syncthreads();
    #pragma unroll
    for (int s = 0; s < 2; ++s) {
      bf16x8 af[4], bfr[4];
      #pragma unroll
      for (int mi = 0; mi < 4; ++mi)
        af[mi] = *reinterpret_cast<const bf16x8*>(
            &As[(wrow + mi * 16 + fl) * 64 + (((s * 4 + fq) ^ fx) * 8)]);
      #pragma unroll
      for (int ni = 0; ni < 4; ++ni)
        bfr[ni] = *reinterpret_cast<const bf16x8*>(
            &Bs[(wcol + ni * 16 + fl) * 64 + (((s * 4 + fq) ^ fx) * 8)]);
      #pragma unroll
      for (int mi = 0; mi < 4; ++mi)
        #pragma unroll
        for (int ni = 0; ni < 4; ++ni)
          acc[mi][ni] = __builtin_amdgcn_mfma_f32_16x16x32_bf16(
              af[mi], bfr[ni], acc[mi][ni], 0, 0, 0);
    }
    __syncthreads();
  }

  // ---- gate-slice stage: A[bm..bm+128) x [bn/2 .. bn/2+64) -> As (16KB).
  {
    const unsigned short* gs = A + (size_t)bm * 512 + (bn >> 1);
    #pragma unroll
    for (int i = 0; i < 4; ++i) {
      int row = i * 32 + (tid >> 3);
      int cb = tid & 7;
      int ss = (cb * 8) ^ ((row & 12) << 2);
      async16(gs + (size_t)row * 512 + ss, &As[row * 64 + cb * 8]);
    }
  }
  asm volatile("s_waitcnt vmcnt(0)" ::: "memory");
  __syncthreads();

  // ---- gate epilogue (xv from LDS, 2-way max bank aliasing = free)
  const int ocb = ((bn + wcol) >> 1) + fl;
  float bnl[2], bg[2];
  #pragma unroll
  for (int p = 0; p < 2; ++p) {
    bnl[p] = bias[ocb + p * 16];
    bg[p]  = bias[512 + ocb + p * 16];
  }
  const int rbase = fq * 4;
  const int crel0 = (wcol >> 1) + fl;
  #pragma unroll
  for (int mi = 0; mi < 4; ++mi) {
    #pragma unroll
    for (int r = 0; r < 4; ++r) {
      int lrow = wrow + mi * 16 + rbase + r;
      int row = bm + lrow;
      #pragma unroll
      for (int p = 0; p < 2; ++p) {
        int oc = ocb + p * 16;
        float xv = us2f(As[lrow * 64 + ((crel0 + p * 16) ^ ((lrow & 12) << 2))]);
        float nl = fmaxf(acc[mi][2 * p][r] + bnl[p], 0.f);
        float g  = 1.f / (1.f + __expf(-(acc[mi][2 * p + 1][r] + bg[p])));
        float res = g * xv + (1.f - g) * nl;
        if (FINAL) Ofp[(size_t)row * 1024 + z * 512 + oc] = res;
        else       Obf[(size_t)z * MS + (size_t)row * 512 + oc] = f2us(res);
      }
    }
  }
}

// ---------------------------------------------------------------------------
// Proj GEMM + fused rel-add (128^2, sliding-window rel-add, XCD swizzle).
__global__ __launch_bounds__(256) void k_gemm_proj(
    const unsigned short* __restrict__ ctx,
    const unsigned short* __restrict__ WTp,    // (2,512,512)
    const unsigned short* __restrict__ nin,    // (B,S2,512)
    const float* __restrict__ lb3, const float* __restrict__ rb3,
    const float* __restrict__ wrel0, const float* __restrict__ wrel1,
    unsigned short* __restrict__ hwx)          // (2,8192,512)
{
  __shared__ unsigned short smem[128 * 136];   // 34.8 KB; staging uses 32 KB
  unsigned short* As = smem;
  unsigned short* Bs = smem + 8192;
  const int K = 512;
  const size_t MS = (size_t)B_ * S_ * D_;

  const int z = blockIdx.z;
  const unsigned short* A = ctx + (size_t)z * MS;
  const unsigned short* BT = WTp + (size_t)z * 512 * 512;
  const float* bias = z ? rb3 : lb3;
  const float* wrel = z ? wrel1 : wrel0;
  const int off = z * WIDTH_;

  const int tid = threadIdx.x;
  const int w = tid >> 6;
  const int l = tid & 63;

  // bijective XCD swizzle within z-plane (256 blocks, %8==0)
  const int gx = gridDim.x;              // 4
  const int nwg = gx * gridDim.y;        // 256
  const int flat = blockIdx.y * gx + blockIdx.x;
  const int cpx = nwg >> 3;              // 32
  const int nf = (flat & 7) * cpx + (flat >> 3);
  const int bm = (nf / gx) * 128;
  const int bn = (nf % gx) * 128;

  const int wrow = (w >> 1) * 64;
  const int wcol = (w & 1) * 64;

  const int lr = l >> 3;
  const int sk = (((l & 7) ^ lr) & 7) * 8;
  const unsigned short* Ap = A + (size_t)(bm + w * 8 + lr) * K + sk;
  const unsigned short* Bp = BT + (size_t)(bn + w * 8 + lr) * K + sk;
  unsigned short* lA = &As[w * 512];
  unsigned short* lB = &Bs[w * 512];
  const size_t K32 = (size_t)32 * K;

  const int fl = l & 15;
  const int fq = l >> 4;
  const int fx = fl & 7;

  f32x4 acc[4][4];
  #pragma unroll
  for (int mi = 0; mi < 4; ++mi)
    #pragma unroll
    for (int ni = 0; ni < 4; ++ni) acc[mi][ni] = (f32x4){0.f, 0.f, 0.f, 0.f};

  for (int k0 = 0; k0 < K; k0 += 64) {
    #pragma unroll
    for (int r = 0; r < 4; ++r) {
      async16(Ap + k0 + r * K32, lA + r * 2048);
      async16(Bp + k0 + r * K32, lB + r * 2048);
    }
    __syncthreads();
    #pragma unroll
    for (int s = 0; s < 2; ++s) {
      bf16x8 af[4], bfr[4];
      #pragma unroll
      for (int mi = 0; mi < 4; ++mi)
        af[mi] = *reinterpret_cast<const bf16x8*>(
            &As[(wrow + mi * 16 + fl) * 64 + (((s * 4 + fq) ^ fx) * 8)]);
      #pragma unroll
      for (int ni = 0; ni < 4; ++ni)
        bfr[ni] = *reinterpret_cast<const bf16x8*>(
            &Bs[(wcol + ni * 16 + fl) * 64 + (((s * 4 + fq) ^ fx) * 8)]);
      #pragma unroll
      for (int mi = 0; mi < 4; ++mi)
        #pragma unroll
        for (int ni = 0; ni < 4; ++ni)
          acc[mi][ni] = __builtin_amdgcn_mfma_f32_16x16x32_bf16(
              af[mi], bfr[ni], acc[mi][ni], 0, 0, 0);
    }
    __syncthreads();
  }

  // stage bias-added tile into LDS (bf16, ld 136)
  float bv[4];
  #pragma unroll
  for (int ni = 0; ni < 4; ++ni) bv[ni] = bias[bn + wcol + ni * 16 + fl];
  const int rbase = (l >> 4) * 4;
  #pragma unroll
  for (int mi = 0; mi < 4; ++mi)
    #pragma unroll
    for (int r = 0; r < 4; ++r)
      #pragma unroll
      for (int ni = 0; ni < 4; ++ni)
        smem[(wrow + mi * 16 + rbase + r) * 136 + wcol + ni * 16 + fl] =
            f2us(acc[mi][ni][r] + bv[ni]);
  __syncthreads();

  // sliding-window rel-add: thread = (8-consecutive-row group, 8-col chunk).
  const float wj[9] = {wrel[0], wrel[1], wrel[2], wrel[3], wrel[4],
                       wrel[5], wrel[6], wrel[7], wrel[8]};
  const int g8 = (tid >> 4) * 8;
  const int tcol = (tid & 15) * 8;
  {
    int gr0 = bm + g8;
    int b0 = gr0 >> 10, s0 = gr0 & (S_ - 1);
    const unsigned short* np =
        nin + ((size_t)b0 * S2_ + off + s0) * D_ + bn + tcol;
    unsigned short* op = hwx + (size_t)z * MS + (size_t)gr0 * D_ + bn + tcol;
    #pragma unroll
    for (int h = 0; h < 2; ++h) {          // rows h*4 .. h*4+3 of the group
      float a4[4][8];
      #pragma unroll
      for (int i = 0; i < 4; ++i)
        unpack8(*reinterpret_cast<const uint4*>(
            &smem[(g8 + h * 4 + i) * 136 + tcol]), a4[i]);
      #pragma unroll
      for (int t = 0; t < 12; ++t) {       // absolute taps h*4 .. h*4+11
        float nf[8];
        unpack8(*reinterpret_cast<const uint4*>(
            np + (size_t)(h * 4 + t) * D_), nf);
        #pragma unroll
        for (int i = 0; i < 4; ++i) {
          if (t < i || t > i + 8) continue;
          float wv = wj[t - i];
          #pragma unroll
          for (int e = 0; e < 8; ++e) a4[i][e] += wv * nf[e];
        }
      }
      #pragma unroll
      for (int i = 0; i < 4; ++i) {
        uint4 o;
        o.x = pack2(a4[i][0], a4[i][1]); o.y = pack2(a4[i][2], a4[i][3]);
        o.z = pack2(a4[i][4], a4[i][5]); o.w = pack2(a4[i][6], a4[i][7]);
        *reinterpret_cast<uint4*>(op + (size_t)(h * 4 + i) * D_) = o;
      }
    }
  }
}

// ---------------------------------------------------------------------------
// Windowed attention, 4 consecutive rows per wave sharing a 13-row K/V
// window; XCD chunk derived from gridDim (r19 bug: hard-coded 2048 factor).
__global__ __launch_bounds__(256) void k_attn_window(
    const unsigned short* __restrict__ qkv,
    unsigned short* __restrict__ ctx)
{
  int nb = ((int)blockIdx.x & 7) * ((int)gridDim.x >> 3)
           + ((int)blockIdx.x >> 3);                    // bijective, %8==0
  int wid = (nb * 256 + (int)threadIdx.x) >> 6;   // dir*2048 + b*256 + sg
  int lane = threadIdx.x & 63;
  int sg = wid & 255;
  int b = (wid >> 8) & 7;
  int dir = wid >> 11;
  int s0 = sg << 2;
  int i0 = s0 + WIDTH_;

  const size_t base = (size_t)b * S2_ * 3072 + dir * 1536;
  const int c0 = lane * 8;

  float qf[4][8];
  #pragma unroll
  for (int r = 0; r < 4; ++r)
    unpack8(*reinterpret_cast<const uint4*>(
        qkv + base + (size_t)(i0 + r) * 3072 + c0), qf[r]);

  float sc[4][10];
  float mx[4] = {-1e30f, -1e30f, -1e30f, -1e30f};
  #pragma unroll
  for (int t = 0; t < 13; ++t) {
    int j = (dir == 0) ? (i0 - 9 + t) : (i0 + t);
    bool ok = (j >= 0 && j < S2_);           // wave-uniform
    float kf[8];
    if (ok)
      unpack8(*reinterpret_cast<const uint4*>(
          qkv + base + (size_t)j * 3072 + 512 + c0), kf);
    #pragma unroll
    for (int r = 0; r < 4; ++r) {
      if (t < r || t > r + 9) continue;      // compile-time prune
      float sv = -1e30f;
      if (ok) {
        float p = qf[r][0] * kf[0];
        #pragma unroll
        for (int e = 1; e < 8; ++e) p += qf[r][e] * kf[e];
        p += __shfl_xor(p, 1);
        p += __shfl_xor(p, 2);
        p += __shfl_xor(p, 4);
        sv = p * 0.125f;
      }
      sc[r][t - r] = sv;
      mx[r] = fmaxf(mx[r], sv);
    }
  }

  float inv[4];
  #pragma unroll
  for (int r = 0; r < 4; ++r) {
    float den = 0.f;
    #pragma unroll
    for (int u = 0; u < 10; ++u) {
      sc[r][u] = (sc[r][u] > -1e29f) ? __expf(sc[r][u] - mx[r]) : 0.f;
      den += sc[r][u];
    }
    inv[r] = 1.f / den;
  }

  float acc[4][8];
  #pragma unroll
  for (int r = 0; r < 4; ++r)
    #pragma unroll
    for (int e = 0; e < 8; ++e) acc[r][e] = 0.f;

  #pragma unroll
  for (int t = 0; t < 13; ++t) {
    int j = (dir == 0) ? (i0 - 9 + t) : (i0 + t);
    bool ok = (j >= 0 && j < S2_);
    float vf[8];
    if (ok)
      unpack8(*reinterpret_cast<const uint4*>(
          qkv + base + (size_t)j * 3072 + 1024 + c0), vf);
    #pragma unroll
    for (int r = 0; r < 4; ++r) {
      if (t < r || t > r + 9) continue;
      if (ok) {
        float p = sc[r][t - r];
        #pragma unroll
        for (int e = 0; e < 8; ++e) acc[r][e] += p * vf[e];
      }
    }
  }

  #pragma unroll
  for (int r = 0; r < 4; ++r) {
    uint4 o;
    o.x = pack2(acc[r][0] * inv[r], acc[r][1] * inv[r]);
    o.y = pack2(acc[r][2] * inv[r], acc[r][3] * inv[r]);
    o.z = pack2(acc[r][4] * inv[r], acc[r][5] * inv[r]);
    o.w = pack2(acc[r][6] * inv[r], acc[r][7] * inv[r]);
    *reinterpret_cast<uint4*>(
        ctx + (((size_t)dir * B_ + b) * S_ + s0 + r) * D_ + c0) = o;
  }
}

// ---------------------------------------------------------------------------
extern "C" void kernel_launch(void* const* d_in, const int* in_sizes, int n_in,
                              void* d_out, int out_size, void* d_ws, size_t ws_size,
                              hipStream_t stream) {
  const float* x    = (const float*)d_in[0];
  const float* lW   = (const float*)d_in[1];
  const float* lb   = (const float*)d_in[2];
  const float* rW   = (const float*)d_in[3];
  const float* rb   = (const float*)d_in[4];
  const float* lpad = (const float*)d_in[5];
  const float* rpad = (const float*)d_in[6];
  const float* lw   = (const float*)d_in[7];
  const float* rw   = (const float*)d_in[8];
  const float* lhwW = (const float*)d_in[9];
  const float* lhwb = (const float*)d_in[10];
  const float* rhwW = (const float*)d_in[11];
  const float* rhwb = (const float*)d_in[12];
  float* out = (float*)d_out;
  unsigned short* ws = (unsigned short*)d_ws;

  const size_t NIN  = (size_t)B_ * S2_ * D_;       // 4,259,840
  const size_t NQKV = (size_t)B_ * S2_ * 3072;     // 25,559,040
  const size_t MS   = (size_t)B_ * S_ * D_;        // 4,194,304
  const size_t DD   = (size_t)D_ * D_;             // 262,144
  const size_t LHW  = (size_t)1024 * 512;          // 524,288

  unsigned short* nin   = ws;
  unsigned short* qkv   = nin + NIN;
  unsigned short* ctx   = qkv + NQKV;              // (2,B,S,D)
  unsigned short* hwx   = ctx + 2 * MS;            // (2,B,S,D)
  unsigned short* hwy   = hwx + 2 * MS;            // (2,B,S,D)
  unsigned short* WTall = hwy + 2 * MS;            // (3072,512)
  unsigned short* WTp   = WTall + 6 * DD;          // (2,512,512)
  unsigned short* hWT   = WTp + 2 * DD;            // (2,2,1024,512)
  float* qkvbias        = (float*)(hWT + 4 * LHW); // 3072 fp32

  // --- prep: 1 dispatch (merged, vectorized) ---
  k_prep<<<2076, 256, 0, stream>>>(lW, rW, lhwW, rhwW, x, lpad, rpad, lb, rb,
                                   WTall, WTp, hWT, nin, qkvbias);

  const int MQ = B_ * S2_;   // 8320

  // --- fused QKV both sides: (8320 x 3072), 128^2 2-phase + XCD swizzle ---
  {
    dim3 g(3072 / 128, MQ / 128, 1);   // (24, 65) -> 1560 blocks, %8==0
    k_gemm_mfma<<<g, 256, 0, stream>>>(nin, WTall, qkvbias, qkv, MQ, 3072, D_);
  }

  // --- attention, both sides, 4 rows/wave, XCD-chunked (fixed) ---
  k_attn_window<<<(2 * B_ * S_) / 16, 256, 0, stream>>>(qkv, ctx);

  // --- proj + fused rel-add, z-batched, XCD swizzle (128^2 kernel) ---
  {
    dim3 g(D_ / 128, (B_ * S_) / 128, 2);   // (4, 64, 2)
    k_gemm_proj<<<g, 256, 0, stream>>>(ctx, WTp, nin, lb + 3 * D_, rb + 3 * D_,
                                       lw, rw, hwx);
  }

  // --- highway layers: 128^2 2-phase + fused gate (LDS xv), z-batched ---
  {
    dim3 g(1024 / 128, (B_ * S_) / 128, 2);   // (8, 64, 2) = 1024 blocks
    k_gemm_hw<false><<<g, 256, 0, stream>>>(hwx, hWT, 2 * LHW,
                                            lhwb, rhwb, hwy, nullptr);
    k_gemm_hw<true><<<g, 256, 0, stream>>>(hwy, hWT + LHW, 2 * LHW,
                                           lhwb + 1024, rhwb + 1024,
                                           nullptr, out);
  }
}